// Round 5
// baseline (169.507 us; speedup 1.0000x reference)
//
#include <hip/hip_runtime.h>
#include <math.h>

// B=1, L=512, D=1024, NH=16, NKV=4, NR=16, HD=RD=64
#define ATTN_SCALE 0.125f
#define REL_SCALE 0.125f

using ushort = unsigned short;
using bf16x8 = __attribute__((ext_vector_type(8))) __bf16;
using floatx4 = __attribute__((ext_vector_type(4))) float;
using ushort8 = __attribute__((ext_vector_type(8))) ushort;
using ushort4v = __attribute__((ext_vector_type(4))) ushort;

__device__ __forceinline__ ushort f2bf(float x) {
  unsigned int u = __builtin_bit_cast(unsigned int, x);
  u += 0x7fffu + ((u >> 16) & 1u);  // RNE
  return (ushort)(u >> 16);
}

// ---------------------------------------------------------------------------
// proj: C[64x64] = A_f32[64][1024] * W_f32[1024][N] (B transposed during LDS
// staging, both operands converted fp32->bf16 in registers). This folds the
// old prep kernel (weight transpose + x/sym convert) into the consumer.
// z = {q(+rope), k(+rope), qr, kr, sv(->svT)}
// ---------------------------------------------------------------------------
__global__ __launch_bounds__(256) void proj_mfma(
    const float* __restrict__ x, const float* __restrict__ symbols,
    const float* __restrict__ wq, const float* __restrict__ wk,
    const float* __restrict__ wqr, const float* __restrict__ wkr,
    const float* __restrict__ wv,
    ushort* __restrict__ qb, ushort* __restrict__ kb, ushort* __restrict__ qrb,
    ushort* __restrict__ krb, ushort* __restrict__ svT,
    const float* __restrict__ fcos, const float* __restrict__ fsin) {
  __shared__ ushort As[64][72];
  __shared__ ushort Bs[64][72];
  const int z = blockIdx.z;
  const float* A = x;
  const float* W;
  ushort* C;
  int N;
  switch (z) {
    case 0: W = wq;  C = qb;  N = 1024; break;
    case 1: W = wk;  C = kb;  N = 256;  break;
    case 2: W = wqr; C = qrb; N = 1024; break;
    case 3: W = wkr; C = krb; N = 1024; break;
    default: A = symbols; W = wv; C = svT; N = 256; break;
  }
  const int bn = blockIdx.x << 6;
  if (bn >= N) return;
  const int bm = blockIdx.y << 6;
  const int tid = threadIdx.x;
  const int sr = tid >> 2, sc = (tid & 3) << 4;   // A staging: row, 16-col chunk
  const int kk = tid >> 4, nl = (tid & 15) << 2;  // B staging: k-row, 4-n chunk
  const int lane = tid & 63;
  const int wy = (tid >> 7) & 1, wx = (tid >> 6) & 1;
  const int lm = lane & 15, lq = lane >> 4;
  const ushort* a_rd = &As[32 * wy + lm][lq * 8];
  const ushort* b_rd = &Bs[32 * wx + lm][lq * 8];
  floatx4 acc[2][2] = {};
  for (int k0 = 0; k0 < 1024; k0 += 64) {
    // A: 4 float4 -> 2 ushort8
    const float* Ap = A + (size_t)(bm + sr) * 1024 + k0 + sc;
    float4 f0 = *(const float4*)(Ap);
    float4 f1 = *(const float4*)(Ap + 4);
    float4 f2 = *(const float4*)(Ap + 8);
    float4 f3 = *(const float4*)(Ap + 12);
    ushort8 av0 = ushort8{f2bf(f0.x), f2bf(f0.y), f2bf(f0.z), f2bf(f0.w),
                          f2bf(f1.x), f2bf(f1.y), f2bf(f1.z), f2bf(f1.w)};
    ushort8 av1 = ushort8{f2bf(f2.x), f2bf(f2.y), f2bf(f2.z), f2bf(f2.w),
                          f2bf(f3.x), f2bf(f3.y), f2bf(f3.z), f2bf(f3.w)};
    // B: 4 passes of coalesced float4 row reads (transposed on LDS write)
    float4 bw[4];
#pragma unroll
    for (int p = 0; p < 4; ++p)
      bw[p] = *(const float4*)(W + (size_t)(k0 + kk + 16 * p) * N + bn + nl);
    __syncthreads();
    *(ushort8*)&As[sr][sc] = av0;
    *(ushort8*)&As[sr][sc + 8] = av1;
#pragma unroll
    for (int p = 0; p < 4; ++p) {
      Bs[nl + 0][kk + 16 * p] = f2bf(bw[p].x);
      Bs[nl + 1][kk + 16 * p] = f2bf(bw[p].y);
      Bs[nl + 2][kk + 16 * p] = f2bf(bw[p].z);
      Bs[nl + 3][kk + 16 * p] = f2bf(bw[p].w);
    }
    __syncthreads();
#pragma unroll
    for (int kh = 0; kh < 2; ++kh) {
      bf16x8 a0 = *(const bf16x8*)(a_rd + kh * 32);
      bf16x8 a1 = *(const bf16x8*)(a_rd + 16 * 72 + kh * 32);
      bf16x8 b0 = *(const bf16x8*)(b_rd + kh * 32);
      bf16x8 b1 = *(const bf16x8*)(b_rd + 16 * 72 + kh * 32);
      acc[0][0] = __builtin_amdgcn_mfma_f32_16x16x32_bf16(a0, b0, acc[0][0], 0, 0, 0);
      acc[0][1] = __builtin_amdgcn_mfma_f32_16x16x32_bf16(a0, b1, acc[0][1], 0, 0, 0);
      acc[1][0] = __builtin_amdgcn_mfma_f32_16x16x32_bf16(a1, b0, acc[1][0], 0, 0, 0);
      acc[1][1] = __builtin_amdgcn_mfma_f32_16x16x32_bf16(a1, b1, acc[1][1], 0, 0, 0);
    }
  }
  if (z <= 1) {
    // fused RoPE: lanes lm, lm^1 hold the (even,odd) pair of d
#pragma unroll
    for (int sy = 0; sy < 2; ++sy)
#pragma unroll
      for (int sx = 0; sx < 2; ++sx)
#pragma unroll
        for (int e = 0; e < 4; ++e) {
          int row = bm + 32 * wy + 16 * sy + 4 * lq + e;
          int col = bn + 32 * wx + 16 * sx + lm;
          float v = acc[sy][sx][e];
          float pv = __shfl_xor(v, 1);
          int d = col & 63, p = d >> 1;
          float c = fcos[(row << 5) + p], s = fsin[(row << 5) + p];
          float o = (d & 1) ? fmaf(pv, s, v * c) : fmaf(v, c, -pv * s);
          C[(size_t)row * N + col] = f2bf(o);
        }
  } else if (z == 4) {
    // write sv transposed: svT[d][j]
#pragma unroll
    for (int sy = 0; sy < 2; ++sy)
#pragma unroll
      for (int sx = 0; sx < 2; ++sx)
#pragma unroll
        for (int e = 0; e < 4; ++e) {
          int row = bm + 32 * wy + 16 * sy + 4 * lq + e;
          int col = bn + 32 * wx + 16 * sx + lm;
          svT[(size_t)col * 512 + row] = f2bf(acc[sy][sx][e]);
        }
  } else {
#pragma unroll
    for (int sy = 0; sy < 2; ++sy)
#pragma unroll
      for (int sx = 0; sx < 2; ++sx)
#pragma unroll
        for (int e = 0; e < 4; ++e) {
          int row = bm + 32 * wy + 16 * sy + 4 * lq + e;
          int col = bn + 32 * wx + 16 * sx + lm;
          C[(size_t)row * N + col] = f2bf(acc[sy][sx][e]);
        }
  }
}

// ---------------------------------------------------------------------------
// relflash: bx<512 -> flash (scores+softmax+attn+asym), longest i-tiles first;
//           bx>=512 -> relations (32x32 (i,j) x 16 r, float4 r-stores).
// ---------------------------------------------------------------------------
__global__ __launch_bounds__(256) void relflash_kernel(
    const ushort* __restrict__ qb, const ushort* __restrict__ kb,
    const ushort* __restrict__ svT, const ushort* __restrict__ qrb,
    const ushort* __restrict__ krb, float* __restrict__ attn,
    float* __restrict__ asym, float* __restrict__ rel) {
  __shared__ float S[16][516];
  __shared__ ushort P[16][520];
  const int bx = blockIdx.x;
  const int tid = threadIdx.x, wave = tid >> 6, lane = tid & 63;
  const int lm = lane & 15, lq = lane >> 4;
  if (bx >= 512) {
    // ---- relations ----
    const int b = bx - 512;
    const int bi0 = (b >> 4) << 5, bj0 = (b & 15) << 5;
    const int ib = bi0 + ((wave >> 1) << 4), jb = bj0 + ((wave & 1) << 4);
    const ushort* qrow = qrb + (size_t)(ib + lm) * 1024 + lq * 8;
    const ushort* krow = krb + (size_t)(jb + lm) * 1024 + lq * 8;
#pragma unroll
    for (int rq = 0; rq < 4; ++rq) {
      floatx4 acc[4];
#pragma unroll
      for (int rr = 0; rr < 4; ++rr) {
        int roff = ((rq << 2) + rr) << 6;
        bf16x8 a0 = *(const bf16x8*)(qrow + roff);
        bf16x8 a1 = *(const bf16x8*)(qrow + roff + 32);
        bf16x8 b0 = *(const bf16x8*)(krow + roff);
        bf16x8 b1 = *(const bf16x8*)(krow + roff + 32);
        floatx4 t = {0.f, 0.f, 0.f, 0.f};
        t = __builtin_amdgcn_mfma_f32_16x16x32_bf16(a0, b0, t, 0, 0, 0);
        t = __builtin_amdgcn_mfma_f32_16x16x32_bf16(a1, b1, t, 0, 0, 0);
        acc[rr] = t;
      }
#pragma unroll
      for (int e = 0; e < 4; ++e) {
        int i = ib + 4 * lq + e, j = jb + lm;
        float4 v = make_float4(acc[0][e] * REL_SCALE, acc[1][e] * REL_SCALE,
                               acc[2][e] * REL_SCALE, acc[3][e] * REL_SCALE);
        *(float4*)(rel + ((size_t)i * 512 + j) * 16 + (rq << 2)) = v;
      }
    }
    return;
  }
  // ---- flash ----
  const int h = bx >> 5, it = 31 - (bx & 31);  // longest tiles dispatched first
  const int i0 = it << 4, kv = h >> 2;
  const int ntiles = it + 1;
  const ushort* qrow = qb + (size_t)(i0 + lm) * 1024 + (h << 6) + lq * 8;
  bf16x8 a0 = *(const bf16x8*)(qrow);
  bf16x8 a1 = *(const bf16x8*)(qrow + 32);
  for (int jt = wave; jt < ntiles; jt += 4) {
    int jb = jt << 4;
    const ushort* krow = kb + (size_t)(jb + lm) * 256 + (kv << 6) + lq * 8;
    bf16x8 b0 = *(const bf16x8*)(krow);
    bf16x8 b1 = *(const bf16x8*)(krow + 32);
    floatx4 acc = {0.f, 0.f, 0.f, 0.f};
    acc = __builtin_amdgcn_mfma_f32_16x16x32_bf16(a0, b0, acc, 0, 0, 0);
    acc = __builtin_amdgcn_mfma_f32_16x16x32_bf16(a1, b1, acc, 0, 0, 0);
#pragma unroll
    for (int e = 0; e < 4; ++e) S[4 * lq + e][jb + lm] = acc[e] * ATTN_SCALE;
  }
  __syncthreads();
  // softmax: 16 threads per row (contiguous within one wave)
  const int row = tid >> 4, t16 = tid & 15;
  const int i = i0 + row;
  const int nj = ntiles << 4;
  float m = -INFINITY;
  for (int s = 0; (s << 6) < nj; ++s) {
    int j4 = (t16 << 2) + (s << 6);
    float4 v = *(const float4*)&S[row][j4];
    if (j4 + 0 <= i) m = fmaxf(m, v.x);
    if (j4 + 1 <= i) m = fmaxf(m, v.y);
    if (j4 + 2 <= i) m = fmaxf(m, v.z);
    if (j4 + 3 <= i) m = fmaxf(m, v.w);
  }
#pragma unroll
  for (int o = 8; o; o >>= 1) m = fmaxf(m, __shfl_xor(m, o, 16));
  // single-expf pass: store masked exp back into S, accumulate sum
  float sum = 0.f;
  for (int s = 0; (s << 6) < nj; ++s) {
    int j4 = (t16 << 2) + (s << 6);
    float4 v = *(const float4*)&S[row][j4];
    v.x = (j4 + 0 <= i) ? __expf(v.x - m) : 0.f;
    v.y = (j4 + 1 <= i) ? __expf(v.y - m) : 0.f;
    v.z = (j4 + 2 <= i) ? __expf(v.z - m) : 0.f;
    v.w = (j4 + 3 <= i) ? __expf(v.w - m) : 0.f;
    sum += v.x + v.y + v.z + v.w;
    *(float4*)&S[row][j4] = v;
  }
#pragma unroll
  for (int o = 8; o; o >>= 1) sum += __shfl_xor(sum, o, 16);
  const float inv = 1.f / sum;
  float* arow = attn + (size_t)h * 262144 + (size_t)i * 512;
  for (int s = 0; s < 8; ++s) {
    int j4 = (t16 << 2) + (s << 6);
    float4 o4 = {0.f, 0.f, 0.f, 0.f};
    if (j4 < nj) {
      float4 v = *(const float4*)&S[row][j4];
      o4.x = v.x * inv;
      o4.y = v.y * inv;
      o4.z = v.z * inv;
      o4.w = v.w * inv;
    }
    *(float4*)(arow + j4) = o4;  // exact zeros above diagonal
    ushort4v p4;
    p4.x = f2bf(o4.x); p4.y = f2bf(o4.y); p4.z = f2bf(o4.z); p4.w = f2bf(o4.w);
    *(ushort4v*)&P[row][j4] = p4;
  }
  __syncthreads();
  // attended_symbols: wave w owns d-range w*16
  const int dbase = wave << 4;
  floatx4 acc2 = {0.f, 0.f, 0.f, 0.f};
  const ushort* svrow = svT + (size_t)((kv << 6) + dbase + lm) * 512;
  const int kmax = (nj + 31) & ~31;  // P zero-filled to 512
  for (int kt = 0; kt < kmax; kt += 32) {
    bf16x8 pa = *(const bf16x8*)&P[lm][kt + lq * 8];
    bf16x8 pb = *(const bf16x8*)(svrow + kt + lq * 8);
    acc2 = __builtin_amdgcn_mfma_f32_16x16x32_bf16(pa, pb, acc2, 0, 0, 0);
  }
#pragma unroll
  for (int e = 0; e < 4; ++e)
    asym[(size_t)(i0 + 4 * lq + e) * 1024 + (h << 6) + dbase + lm] = acc2[e];
}

// ---------------------------------------------------------------------------
// tker+combine: T[i,h,r] = sum_j attn[h,i,j]*rel[i,j,r]; then
// attb[i,h,d] = bf16(asym[i,h,d] + sum_r T*wr[r,h*64+d]).
// ---------------------------------------------------------------------------
__global__ __launch_bounds__(256) void tker_combine(const float* __restrict__ attn,
                                                    const float* __restrict__ rel,
                                                    const float* __restrict__ asym,
                                                    const float* __restrict__ wr,
                                                    ushort* __restrict__ attb) {
  const int i = blockIdx.x, tid = threadIdx.x;
  __shared__ float a_s[16][132];
  __shared__ float r_s[16][132];
  __shared__ float Ts[16][17];
  const int h = tid >> 4, r = tid & 15;
  float acc = 0.f;
  for (int j0 = 0; j0 <= i; j0 += 128) {
#pragma unroll
    for (int idx = tid; idx < 512; idx += 256) {
      int hh = idx >> 5, j4 = (idx & 31) << 2;
      *(float4*)&a_s[hh][j4] =
          *(const float4*)(attn + (size_t)hh * 262144 + (size_t)i * 512 + j0 + j4);
    }
#pragma unroll
    for (int idx = tid; idx < 512; idx += 256) {
      int j = idx >> 2, r4 = (idx & 3) << 2;
      float4 v = *(const float4*)(rel + ((size_t)i * 512 + j0 + j) * 16 + r4);
      r_s[r4 + 0][j] = v.x;
      r_s[r4 + 1][j] = v.y;
      r_s[r4 + 2][j] = v.z;
      r_s[r4 + 3][j] = v.w;
    }
    __syncthreads();
#pragma unroll
    for (int jj = 0; jj < 128; jj += 4) {  // attn beyond i is exactly 0
      float4 a4 = *(const float4*)&a_s[h][jj];
      float4 r4v = *(const float4*)&r_s[r][jj];
      acc = fmaf(a4.x, r4v.x, acc);
      acc = fmaf(a4.y, r4v.y, acc);
      acc = fmaf(a4.z, r4v.z, acc);
      acc = fmaf(a4.w, r4v.w, acc);
    }
    __syncthreads();
  }
  Ts[h][r] = acc;
  __syncthreads();
  const int hc = tid >> 4, d4 = (tid & 15) << 2;
  float4 o = *(const float4*)(asym + (size_t)i * 1024 + (hc << 6) + d4);
#pragma unroll
  for (int rr = 0; rr < 16; ++rr) {
    float tv = Ts[hc][rr];
    float4 w4 = *(const float4*)(wr + (size_t)rr * 1024 + (hc << 6) + d4);
    o.x = fmaf(tv, w4.x, o.x);
    o.y = fmaf(tv, w4.y, o.y);
    o.z = fmaf(tv, w4.z, o.z);
    o.w = fmaf(tv, w4.w, o.w);
  }
  ushort4v ob;
  ob.x = f2bf(o.x); ob.y = f2bf(o.y); ob.z = f2bf(o.z); ob.w = f2bf(o.w);
  *(ushort4v*)(attb + (size_t)i * 1024 + (hc << 6) + d4) = ob;
}

// ---------------------------------------------------------------------------
// out = attb @ wo: 64x32 tiles, wo transposed+converted during LDS staging.
// ---------------------------------------------------------------------------
__global__ __launch_bounds__(256) void out_mfma(const ushort* __restrict__ attb,
                                                const float* __restrict__ wo,
                                                float* __restrict__ out) {
  __shared__ ushort As[64][72];
  __shared__ ushort Bs[32][72];
  const int bn = blockIdx.x << 5, bm = blockIdx.y << 6;
  const int tid = threadIdx.x;
  const int sr = tid >> 2, sc = (tid & 3) << 4;   // A stage: 16 elems
  const int kk = tid >> 3, nl = (tid & 7) << 2;   // B stage: k-row, 4-n chunk
  const int lane = tid & 63;
  const int wy = (tid >> 7) & 1, wx = (tid >> 6) & 1;
  const int lm = lane & 15, lq = lane >> 4;
  const ushort* a_rd = &As[32 * wy + lm][lq * 8];
  const ushort* b_rd = &Bs[16 * wx + lm][lq * 8];
  floatx4 acc[2] = {};
  for (int k0 = 0; k0 < 1024; k0 += 64) {
    const ushort* Ap = attb + (size_t)(bm + sr) * 1024 + k0 + sc;
    ushort8 av0 = *(const ushort8*)Ap;
    ushort8 av1 = *(const ushort8*)(Ap + 8);
    float4 bw[2];
#pragma unroll
    for (int p = 0; p < 2; ++p)
      bw[p] = *(const float4*)(wo + (size_t)(k0 + kk + 32 * p) * 1024 + bn + nl);
    __syncthreads();
    *(ushort8*)&As[sr][sc] = av0;
    *(ushort8*)&As[sr][sc + 8] = av1;
#pragma unroll
    for (int p = 0; p < 2; ++p) {
      Bs[nl + 0][kk + 32 * p] = f2bf(bw[p].x);
      Bs[nl + 1][kk + 32 * p] = f2bf(bw[p].y);
      Bs[nl + 2][kk + 32 * p] = f2bf(bw[p].z);
      Bs[nl + 3][kk + 32 * p] = f2bf(bw[p].w);
    }
    __syncthreads();
#pragma unroll
    for (int kh = 0; kh < 2; ++kh) {
      bf16x8 a0 = *(const bf16x8*)(a_rd + kh * 32);
      bf16x8 a1 = *(const bf16x8*)(a_rd + 16 * 72 + kh * 32);
      bf16x8 b0 = *(const bf16x8*)(b_rd + kh * 32);
      acc[0] = __builtin_amdgcn_mfma_f32_16x16x32_bf16(a0, b0, acc[0], 0, 0, 0);
      acc[1] = __builtin_amdgcn_mfma_f32_16x16x32_bf16(a1, b0, acc[1], 0, 0, 0);
    }
  }
#pragma unroll
  for (int sy = 0; sy < 2; ++sy)
#pragma unroll
    for (int e = 0; e < 4; ++e) {
      int row = bm + 32 * wy + 16 * sy + 4 * lq + e;
      int col = bn + 16 * wx + lm;
      out[(size_t)row * 1024 + col] = acc[sy][e];
    }
}

extern "C" void kernel_launch(void* const* d_in, const int* in_sizes, int n_in,
                              void* d_out, int out_size, void* d_ws, size_t ws_size,
                              hipStream_t stream) {
  const float* x       = (const float*)d_in[0];
  const float* symbols = (const float*)d_in[1];
  const float* fcos    = (const float*)d_in[2];
  const float* fsin    = (const float*)d_in[3];
  const float* wq_attn = (const float*)d_in[4];
  const float* wk_attn = (const float*)d_in[5];
  const float* wq_rel  = (const float*)d_in[6];
  const float* wk_rel  = (const float*)d_in[7];
  const float* wr      = (const float*)d_in[8];
  const float* wv      = (const float*)d_in[9];
  const float* wo      = (const float*)d_in[10];

  float* out  = (float*)d_out;   // 512*1024
  float* attn = out + 524288;    // 16*512*512
  float* rel  = attn + 4194304;  // 512*512*16

  char* wsb = (char*)d_ws;
  const size_t KB = 1024;
  ushort* qb   = (ushort*)(wsb);               // 1 MB
  ushort* kb   = (ushort*)(wsb + 1024 * KB);   // 0.25 MB
  ushort* qrb  = (ushort*)(wsb + 1280 * KB);   // 1 MB
  ushort* krb  = (ushort*)(wsb + 2304 * KB);   // 1 MB
  ushort* svT  = (ushort*)(wsb + 3328 * KB);   // 0.25 MB
  float*  asym = (float*)(wsb + 3584 * KB);    // 2 MB
  ushort* attb = (ushort*)(wsb + 5632 * KB);   // 1 MB

  proj_mfma<<<dim3(16, 8, 5), 256, 0, stream>>>(x, symbols, wq_attn, wk_attn,
                                                wq_rel, wk_rel, wv,
                                                qb, kb, qrb, krb, svT, fcos, fsin);
  relflash_kernel<<<dim3(768), 256, 0, stream>>>(qb, kb, svT, qrb, krb, attn, asym, rel);
  tker_combine<<<dim3(512), 256, 0, stream>>>(attn, rel, asym, wr, attb);
  out_mfma<<<dim3(32, 8), 256, 0, stream>>>(attb, wo, out);
}

// Round 6
// 152.911 us; speedup vs baseline: 1.1085x; 1.1085x over previous
//
#include <hip/hip_runtime.h>
#include <math.h>

// B=1, L=512, D=1024, NH=16, NKV=4, NR=16, HD=RD=64
#define ATTN_SCALE 0.125f
#define REL_SCALE 0.125f

using ushort = unsigned short;
using bf16x8 = __attribute__((ext_vector_type(8))) __bf16;
using floatx4 = __attribute__((ext_vector_type(4))) float;
using ushort8 = __attribute__((ext_vector_type(8))) ushort;
using ushort4v = __attribute__((ext_vector_type(4))) ushort;

__device__ __forceinline__ ushort f2bf(float x) {
  unsigned int u = __builtin_bit_cast(unsigned int, x);
  u += 0x7fffu + ((u >> 16) & 1u);  // RNE
  return (ushort)(u >> 16);
}

// ---------------------------------------------------------------------------
// 64x64 MFMA GEMM body (proj): C = A[64][K] * Bt[64][K]^T, all bf16.
// Conflict-free: ushort8 LDS stores, padded rows (72).
// ---------------------------------------------------------------------------
__device__ __forceinline__ void mfma_body(const ushort* __restrict__ A, int lda,
                                          const ushort* __restrict__ Bt, int ldb,
                                          int K, floatx4 (&acc)[2][2]) {
  __shared__ ushort As[64][72];
  __shared__ ushort Bs[64][72];
  const int tid = threadIdx.x;
  const int sr = tid >> 2, sc = (tid & 3) << 4;
  const int lane = tid & 63;
  const int wy = (tid >> 7) & 1, wx = (tid >> 6) & 1;
  const int lm = lane & 15, lq = lane >> 4;
  const ushort* a_rd = &As[32 * wy + lm][lq * 8];
  const ushort* b_rd = &Bs[32 * wx + lm][lq * 8];
  for (int k0 = 0; k0 < K; k0 += 64) {
    const ushort* Ap = A + (size_t)sr * lda + k0 + sc;
    ushort8 av0 = *(const ushort8*)Ap;
    ushort8 av1 = *(const ushort8*)(Ap + 8);
    const ushort* Bp = Bt + (size_t)sr * ldb + k0 + sc;
    ushort8 bv0 = *(const ushort8*)Bp;
    ushort8 bv1 = *(const ushort8*)(Bp + 8);
    __syncthreads();
    *(ushort8*)&As[sr][sc] = av0;
    *(ushort8*)&As[sr][sc + 8] = av1;
    *(ushort8*)&Bs[sr][sc] = bv0;
    *(ushort8*)&Bs[sr][sc + 8] = bv1;
    __syncthreads();
#pragma unroll
    for (int kh = 0; kh < 2; ++kh) {
      bf16x8 a0 = *(const bf16x8*)(a_rd + kh * 32);
      bf16x8 a1 = *(const bf16x8*)(a_rd + 16 * 72 + kh * 32);
      bf16x8 b0 = *(const bf16x8*)(b_rd + kh * 32);
      bf16x8 b1 = *(const bf16x8*)(b_rd + 16 * 72 + kh * 32);
      acc[0][0] = __builtin_amdgcn_mfma_f32_16x16x32_bf16(a0, b0, acc[0][0], 0, 0, 0);
      acc[0][1] = __builtin_amdgcn_mfma_f32_16x16x32_bf16(a0, b1, acc[0][1], 0, 0, 0);
      acc[1][0] = __builtin_amdgcn_mfma_f32_16x16x32_bf16(a1, b0, acc[1][0], 0, 0, 0);
      acc[1][1] = __builtin_amdgcn_mfma_f32_16x16x32_bf16(a1, b1, acc[1][1], 0, 0, 0);
    }
  }
}

#define EPILOG_VARS                                                   \
  const int lane = threadIdx.x & 63;                                  \
  const int wy = (threadIdx.x >> 7) & 1, wx = (threadIdx.x >> 6) & 1; \
  const int lm = lane & 15, lq = lane >> 4;

// ---------------------------------------------------------------------------
// prep: z=0..5 weight transpose+convert (conflict-free 32x33 LDS transpose);
//       z=6 x/symbols fp32->bf16
// ---------------------------------------------------------------------------
__global__ __launch_bounds__(256) void prep_kernel(
    const float* __restrict__ x, const float* __restrict__ sym,
    const float* __restrict__ wq, const float* __restrict__ wk,
    const float* __restrict__ wqr, const float* __restrict__ wkr,
    const float* __restrict__ wv, const float* __restrict__ wo,
    ushort* __restrict__ xb, ushort* __restrict__ symb,
    ushort* __restrict__ wqT, ushort* __restrict__ wkT, ushort* __restrict__ wqrT,
    ushort* __restrict__ wkrT, ushort* __restrict__ wvT, ushort* __restrict__ woT) {
  if (blockIdx.z == 6) {
    int b = blockIdx.y * 32 + blockIdx.x;
    if (b >= 512) return;
    int idx = b * 256 + threadIdx.x;
    int i4 = idx << 2;
    float4 v = *(const float4*)(x + i4);
    uint2 o;
    o.x = (unsigned)f2bf(v.x) | ((unsigned)f2bf(v.y) << 16);
    o.y = (unsigned)f2bf(v.z) | ((unsigned)f2bf(v.w) << 16);
    *(uint2*)(xb + i4) = o;
    float4 w = *(const float4*)(sym + i4);
    o.x = (unsigned)f2bf(w.x) | ((unsigned)f2bf(w.y) << 16);
    o.y = (unsigned)f2bf(w.z) | ((unsigned)f2bf(w.w) << 16);
    *(uint2*)(symb + i4) = o;
    return;
  }
  __shared__ ushort t[32][33];
  const float* in;
  ushort* out;
  int N;
  switch (blockIdx.z) {
    case 0: in = wq;  out = wqT;  N = 1024; break;
    case 1: in = wk;  out = wkT;  N = 256;  break;
    case 2: in = wqr; out = wqrT; N = 1024; break;
    case 3: in = wkr; out = wkrT; N = 1024; break;
    case 4: in = wv;  out = wvT;  N = 256;  break;
    default: in = wo; out = woT;  N = 1024; break;
  }
  int n0 = blockIdx.x << 5;
  if (n0 >= N) return;
  int k0 = blockIdx.y << 5;
  int tx = threadIdx.x & 31, ty = threadIdx.x >> 5;
#pragma unroll
  for (int rr = 0; rr < 32; rr += 8)
    t[ty + rr][tx] = f2bf(in[(size_t)(k0 + ty + rr) * N + n0 + tx]);
  __syncthreads();
#pragma unroll
  for (int rr = 0; rr < 32; rr += 8)
    out[(size_t)(n0 + ty + rr) * 1024 + k0 + tx] = t[tx][ty + rr];
}

// ---------------------------------------------------------------------------
// proj: z = {q(+rope), k(+rope), qr, kr, sv(->svT)} — all-bf16 operands
// ---------------------------------------------------------------------------
__global__ __launch_bounds__(256) void proj_mfma(
    const ushort* __restrict__ xb, const ushort* __restrict__ symb,
    const ushort* __restrict__ wqT, const ushort* __restrict__ wkT,
    const ushort* __restrict__ wqrT, const ushort* __restrict__ wkrT,
    const ushort* __restrict__ wvT,
    ushort* __restrict__ qb, ushort* __restrict__ kb, ushort* __restrict__ qrb,
    ushort* __restrict__ krb, ushort* __restrict__ svT,
    const float* __restrict__ fcos, const float* __restrict__ fsin) {
  const int z = blockIdx.z;
  const ushort* A = xb;
  const ushort* Bt;
  ushort* C;
  int N;
  switch (z) {
    case 0: Bt = wqT;  C = qb;  N = 1024; break;
    case 1: Bt = wkT;  C = kb;  N = 256;  break;
    case 2: Bt = wqrT; C = qrb; N = 1024; break;
    case 3: Bt = wkrT; C = krb; N = 1024; break;
    default: A = symb; Bt = wvT; C = svT; N = 256; break;
  }
  const int bn = blockIdx.x << 6;
  if (bn >= N) return;
  const int bm = blockIdx.y << 6;
  floatx4 acc[2][2] = {};
  mfma_body(A + (size_t)bm * 1024, 1024, Bt + (size_t)bn * 1024, 1024, 1024, acc);
  EPILOG_VARS
  if (z <= 1) {
    // fused RoPE: lanes lm, lm^1 hold the (even,odd) pair of d
#pragma unroll
    for (int sy = 0; sy < 2; ++sy)
#pragma unroll
      for (int sx = 0; sx < 2; ++sx)
#pragma unroll
        for (int e = 0; e < 4; ++e) {
          int row = bm + 32 * wy + 16 * sy + 4 * lq + e;
          int col = bn + 32 * wx + 16 * sx + lm;
          float v = acc[sy][sx][e];
          float pv = __shfl_xor(v, 1);
          int d = col & 63, p = d >> 1;
          float c = fcos[(row << 5) + p], s = fsin[(row << 5) + p];
          float o = (d & 1) ? fmaf(pv, s, v * c) : fmaf(v, c, -pv * s);
          C[(size_t)row * N + col] = f2bf(o);
        }
  } else if (z == 4) {
    // write sv transposed: svT[d][j]
#pragma unroll
    for (int sy = 0; sy < 2; ++sy)
#pragma unroll
      for (int sx = 0; sx < 2; ++sx)
#pragma unroll
        for (int e = 0; e < 4; ++e) {
          int row = bm + 32 * wy + 16 * sy + 4 * lq + e;
          int col = bn + 32 * wx + 16 * sx + lm;
          svT[(size_t)col * 512 + row] = f2bf(acc[sy][sx][e]);
        }
  } else {
#pragma unroll
    for (int sy = 0; sy < 2; ++sy)
#pragma unroll
      for (int sx = 0; sx < 2; ++sx)
#pragma unroll
        for (int e = 0; e < 4; ++e) {
          int row = bm + 32 * wy + 16 * sy + 4 * lq + e;
          int col = bn + 32 * wx + 16 * sx + lm;
          C[(size_t)row * N + col] = f2bf(acc[sy][sx][e]);
        }
  }
}

// ---------------------------------------------------------------------------
// relflash: bx<512 -> flash (scores+softmax+attn+asym), longest i-tiles first;
//           bx>=512 -> relations: writes fp32 rel (r-innermost, float4) AND a
//           bf16 transposed copy rel_bT[i][r][j] for the T-MFMA kernel.
// ---------------------------------------------------------------------------
__global__ __launch_bounds__(256) void relflash_kernel(
    const ushort* __restrict__ qb, const ushort* __restrict__ kb,
    const ushort* __restrict__ svT, const ushort* __restrict__ qrb,
    const ushort* __restrict__ krb, float* __restrict__ attn,
    float* __restrict__ asym, float* __restrict__ rel,
    ushort* __restrict__ rel_bT) {
  __shared__ float S[16][516];
  __shared__ ushort P[16][520];
  const int bx = blockIdx.x;
  const int tid = threadIdx.x, wave = tid >> 6, lane = tid & 63;
  const int lm = lane & 15, lq = lane >> 4;
  if (bx >= 512) {
    // ---- relations ----
    const int b = bx - 512;
    const int bi0 = (b >> 4) << 5, bj0 = (b & 15) << 5;
    const int ib = bi0 + ((wave >> 1) << 4), jb = bj0 + ((wave & 1) << 4);
    const ushort* qrow = qrb + (size_t)(ib + lm) * 1024 + lq * 8;
    const ushort* krow = krb + (size_t)(jb + lm) * 1024 + lq * 8;
#pragma unroll
    for (int rq = 0; rq < 4; ++rq) {
      floatx4 acc[4];
#pragma unroll
      for (int rr = 0; rr < 4; ++rr) {
        int roff = ((rq << 2) + rr) << 6;
        bf16x8 a0 = *(const bf16x8*)(qrow + roff);
        bf16x8 a1 = *(const bf16x8*)(qrow + roff + 32);
        bf16x8 b0 = *(const bf16x8*)(krow + roff);
        bf16x8 b1 = *(const bf16x8*)(krow + roff + 32);
        floatx4 t = {0.f, 0.f, 0.f, 0.f};
        t = __builtin_amdgcn_mfma_f32_16x16x32_bf16(a0, b0, t, 0, 0, 0);
        t = __builtin_amdgcn_mfma_f32_16x16x32_bf16(a1, b1, t, 0, 0, 0);
        acc[rr] = t;
      }
#pragma unroll
      for (int e = 0; e < 4; ++e) {
        int i = ib + 4 * lq + e, j = jb + lm;
        float4 v = make_float4(acc[0][e] * REL_SCALE, acc[1][e] * REL_SCALE,
                               acc[2][e] * REL_SCALE, acc[3][e] * REL_SCALE);
        *(float4*)(rel + ((size_t)i * 512 + j) * 16 + (rq << 2)) = v;
        // bf16 transposed side-copy for the T-MFMA: rel_bT[i][r][j]
        size_t tb = (size_t)i * 8192 + (size_t)(rq << 2) * 512 + j;
        rel_bT[tb]         = f2bf(v.x);
        rel_bT[tb + 512]   = f2bf(v.y);
        rel_bT[tb + 1024]  = f2bf(v.z);
        rel_bT[tb + 1536]  = f2bf(v.w);
      }
    }
    return;
  }
  // ---- flash ----
  const int h = bx >> 5, it = 31 - (bx & 31);  // longest tiles dispatched first
  const int i0 = it << 4, kv = h >> 2;
  const int ntiles = it + 1;
  const ushort* qrow = qb + (size_t)(i0 + lm) * 1024 + (h << 6) + lq * 8;
  bf16x8 a0 = *(const bf16x8*)(qrow);
  bf16x8 a1 = *(const bf16x8*)(qrow + 32);
  for (int jt = wave; jt < ntiles; jt += 4) {
    int jb = jt << 4;
    const ushort* krow = kb + (size_t)(jb + lm) * 256 + (kv << 6) + lq * 8;
    bf16x8 b0 = *(const bf16x8*)(krow);
    bf16x8 b1 = *(const bf16x8*)(krow + 32);
    floatx4 acc = {0.f, 0.f, 0.f, 0.f};
    acc = __builtin_amdgcn_mfma_f32_16x16x32_bf16(a0, b0, acc, 0, 0, 0);
    acc = __builtin_amdgcn_mfma_f32_16x16x32_bf16(a1, b1, acc, 0, 0, 0);
#pragma unroll
    for (int e = 0; e < 4; ++e) S[4 * lq + e][jb + lm] = acc[e] * ATTN_SCALE;
  }
  __syncthreads();
  const int row = tid >> 4, t16 = tid & 15;
  const int i = i0 + row;
  const int nj = ntiles << 4;
  float m = -INFINITY;
  for (int s = 0; (s << 6) < nj; ++s) {
    int j4 = (t16 << 2) + (s << 6);
    float4 v = *(const float4*)&S[row][j4];
    if (j4 + 0 <= i) m = fmaxf(m, v.x);
    if (j4 + 1 <= i) m = fmaxf(m, v.y);
    if (j4 + 2 <= i) m = fmaxf(m, v.z);
    if (j4 + 3 <= i) m = fmaxf(m, v.w);
  }
#pragma unroll
  for (int o = 8; o; o >>= 1) m = fmaxf(m, __shfl_xor(m, o, 16));
  // single-expf pass: store masked exp back into S, accumulate sum
  float sum = 0.f;
  for (int s = 0; (s << 6) < nj; ++s) {
    int j4 = (t16 << 2) + (s << 6);
    float4 v = *(const float4*)&S[row][j4];
    v.x = (j4 + 0 <= i) ? __expf(v.x - m) : 0.f;
    v.y = (j4 + 1 <= i) ? __expf(v.y - m) : 0.f;
    v.z = (j4 + 2 <= i) ? __expf(v.z - m) : 0.f;
    v.w = (j4 + 3 <= i) ? __expf(v.w - m) : 0.f;
    sum += v.x + v.y + v.z + v.w;
    *(float4*)&S[row][j4] = v;
  }
#pragma unroll
  for (int o = 8; o; o >>= 1) sum += __shfl_xor(sum, o, 16);
  const float inv = 1.f / sum;
  float* arow = attn + (size_t)h * 262144 + (size_t)i * 512;
  for (int s = 0; s < 8; ++s) {
    int j4 = (t16 << 2) + (s << 6);
    float4 o4 = {0.f, 0.f, 0.f, 0.f};
    if (j4 < nj) {
      float4 v = *(const float4*)&S[row][j4];
      o4.x = v.x * inv;
      o4.y = v.y * inv;
      o4.z = v.z * inv;
      o4.w = v.w * inv;
    }
    *(float4*)(arow + j4) = o4;  // exact zeros above diagonal
    ushort4v p4;
    p4.x = f2bf(o4.x); p4.y = f2bf(o4.y); p4.z = f2bf(o4.z); p4.w = f2bf(o4.w);
    *(ushort4v*)&P[row][j4] = p4;
  }
  __syncthreads();
  // attended_symbols: wave w owns d-range w*16
  const int dbase = wave << 4;
  floatx4 acc2 = {0.f, 0.f, 0.f, 0.f};
  const ushort* svrow = svT + (size_t)((kv << 6) + dbase + lm) * 512;
  const int kmax = (nj + 31) & ~31;  // P zero-filled to 512
  for (int kt = 0; kt < kmax; kt += 32) {
    bf16x8 pa = *(const bf16x8*)&P[lm][kt + lq * 8];
    bf16x8 pb = *(const bf16x8*)(svrow + kt + lq * 8);
    acc2 = __builtin_amdgcn_mfma_f32_16x16x32_bf16(pa, pb, acc2, 0, 0, 0);
  }
#pragma unroll
  for (int e = 0; e < 4; ++e)
    asym[(size_t)(i0 + 4 * lq + e) * 1024 + (h << 6) + dbase + lm] = acc2[e];
}

// ---------------------------------------------------------------------------
// tker+combine via MFMA: per i, T[16h x 16r] = attn_rows(i) (16x512) *
// rel_bT[i]^T — one mfma_16x16x32 chain per wave (wave w -> i = 4*bx + w).
// A-frag: lane lm = h, read fp32 attn row, convert in-reg (causally capped).
// B-frag: lane lm = r, bf16 rel_bT contiguous j.
// Then att[i,h,d] = asym + sum_r T[h][r]*wr[r][h*64+d] via LDS Ts.
// ---------------------------------------------------------------------------
__global__ __launch_bounds__(256) void tker_combine(const float* __restrict__ attn,
                                                    const ushort* __restrict__ rel_bT,
                                                    const float* __restrict__ asym,
                                                    const float* __restrict__ wr,
                                                    ushort* __restrict__ attb) {
  const int i0 = blockIdx.x << 2;
  const int tid = threadIdx.x, wave = tid >> 6, lane = tid & 63;
  const int lm = lane & 15, lq = lane >> 4;
  const int i = i0 + wave;
  __shared__ float Ts[4][16][17];
  floatx4 acc = {0.f, 0.f, 0.f, 0.f};
  const float* arow = attn + (size_t)lm * 262144 + (size_t)i * 512;  // h = lm
  const ushort* brow = rel_bT + (size_t)i * 8192 + (size_t)lm * 512; // r = lm
  const int ktiles = (i >> 5) + 1;  // attn is exactly 0 for j > i
  for (int kt = 0; kt < ktiles; ++kt) {
    int k = (kt << 5) + lq * 8;
    float4 f0 = *(const float4*)(arow + k);
    float4 f1 = *(const float4*)(arow + k + 4);
    bf16x8 a = __builtin_bit_cast(bf16x8,
        ushort8{f2bf(f0.x), f2bf(f0.y), f2bf(f0.z), f2bf(f0.w),
                f2bf(f1.x), f2bf(f1.y), f2bf(f1.z), f2bf(f1.w)});
    bf16x8 b = *(const bf16x8*)(brow + k);
    acc = __builtin_amdgcn_mfma_f32_16x16x32_bf16(a, b, acc, 0, 0, 0);
  }
  // C layout: col(lm)=r, row(4*lq+e)=h
#pragma unroll
  for (int e = 0; e < 4; ++e) Ts[wave][4 * lq + e][lm] = acc[e];
  __syncthreads();
  const int hc = tid >> 4, d4 = (tid & 15) << 2;
  float4 o[4];
#pragma unroll
  for (int iw = 0; iw < 4; ++iw)
    o[iw] = *(const float4*)(asym + (size_t)(i0 + iw) * 1024 + (hc << 6) + d4);
#pragma unroll
  for (int rr = 0; rr < 16; ++rr) {
    float4 w4 = *(const float4*)(wr + (size_t)rr * 1024 + (hc << 6) + d4);
#pragma unroll
    for (int iw = 0; iw < 4; ++iw) {
      float tv = Ts[iw][hc][rr];
      o[iw].x = fmaf(tv, w4.x, o[iw].x);
      o[iw].y = fmaf(tv, w4.y, o[iw].y);
      o[iw].z = fmaf(tv, w4.z, o[iw].z);
      o[iw].w = fmaf(tv, w4.w, o[iw].w);
    }
  }
#pragma unroll
  for (int iw = 0; iw < 4; ++iw) {
    ushort4v ob;
    ob.x = f2bf(o[iw].x); ob.y = f2bf(o[iw].y);
    ob.z = f2bf(o[iw].z); ob.w = f2bf(o[iw].w);
    *(ushort4v*)(attb + (size_t)(i0 + iw) * 1024 + (hc << 6) + d4) = ob;
  }
}

// ---------------------------------------------------------------------------
// out = attb @ wo: 64x32 tiles (256 blocks), bf16 operands (woT from prep).
// ---------------------------------------------------------------------------
__global__ __launch_bounds__(256) void out_mfma(const ushort* __restrict__ attb,
                                                const ushort* __restrict__ woT,
                                                float* __restrict__ out) {
  __shared__ ushort As[64][72];
  __shared__ ushort Bs[32][72];
  const int bn = blockIdx.x << 5, bm = blockIdx.y << 6;
  const int tid = threadIdx.x;
  const int sr = tid >> 2, sc = (tid & 3) << 4;  // A stage: 16 elems
  const int br = tid >> 3, bc = (tid & 7) << 3;  // B stage: 8 elems
  const int lane = tid & 63;
  const int wy = (tid >> 7) & 1, wx = (tid >> 6) & 1;
  const int lm = lane & 15, lq = lane >> 4;
  const ushort* a_rd = &As[32 * wy + lm][lq * 8];
  const ushort* b_rd = &Bs[16 * wx + lm][lq * 8];
  floatx4 acc[2] = {};
  for (int k0 = 0; k0 < 1024; k0 += 64) {
    const ushort* Ap = attb + (size_t)(bm + sr) * 1024 + k0 + sc;
    ushort8 av0 = *(const ushort8*)Ap;
    ushort8 av1 = *(const ushort8*)(Ap + 8);
    ushort8 bv = *(const ushort8*)(woT + (size_t)(bn + br) * 1024 + k0 + bc);
    __syncthreads();
    *(ushort8*)&As[sr][sc] = av0;
    *(ushort8*)&As[sr][sc + 8] = av1;
    *(ushort8*)&Bs[br][bc] = bv;
    __syncthreads();
#pragma unroll
    for (int kh = 0; kh < 2; ++kh) {
      bf16x8 a0 = *(const bf16x8*)(a_rd + kh * 32);
      bf16x8 a1 = *(const bf16x8*)(a_rd + 16 * 72 + kh * 32);
      bf16x8 b0 = *(const bf16x8*)(b_rd + kh * 32);
      acc[0] = __builtin_amdgcn_mfma_f32_16x16x32_bf16(a0, b0, acc[0], 0, 0, 0);
      acc[1] = __builtin_amdgcn_mfma_f32_16x16x32_bf16(a1, b0, acc[1], 0, 0, 0);
    }
  }
#pragma unroll
  for (int sy = 0; sy < 2; ++sy)
#pragma unroll
    for (int e = 0; e < 4; ++e) {
      int row = bm + 32 * wy + 16 * sy + 4 * lq + e;
      int col = bn + 16 * wx + lm;
      out[(size_t)row * 1024 + col] = acc[sy][e];
    }
}

extern "C" void kernel_launch(void* const* d_in, const int* in_sizes, int n_in,
                              void* d_out, int out_size, void* d_ws, size_t ws_size,
                              hipStream_t stream) {
  const float* x       = (const float*)d_in[0];
  const float* symbols = (const float*)d_in[1];
  const float* fcos    = (const float*)d_in[2];
  const float* fsin    = (const float*)d_in[3];
  const float* wq_attn = (const float*)d_in[4];
  const float* wk_attn = (const float*)d_in[5];
  const float* wq_rel  = (const float*)d_in[6];
  const float* wk_rel  = (const float*)d_in[7];
  const float* wr      = (const float*)d_in[8];
  const float* wv      = (const float*)d_in[9];
  const float* wo      = (const float*)d_in[10];

  float* out  = (float*)d_out;   // 512*1024
  float* attn = out + 524288;    // 16*512*512
  float* rel  = attn + 4194304;  // 512*512*16

  char* wsb = (char*)d_ws;
  const size_t KB = 1024;
  ushort* xb     = (ushort*)(wsb);                 // 1 MB
  ushort* symb   = (ushort*)(wsb + 1024 * KB);     // 1 MB
  ushort* wqT    = (ushort*)(wsb + 2048 * KB);     // 2 MB
  ushort* wkT    = (ushort*)(wsb + 4096 * KB);     // 0.5 MB
  ushort* wqrT   = (ushort*)(wsb + 4608 * KB);     // 2 MB
  ushort* wkrT   = (ushort*)(wsb + 6656 * KB);     // 2 MB
  ushort* wvT    = (ushort*)(wsb + 8704 * KB);     // 0.5 MB
  ushort* woT    = (ushort*)(wsb + 9216 * KB);     // 2 MB
  ushort* qb     = (ushort*)(wsb + 11264 * KB);    // 1 MB
  ushort* kb     = (ushort*)(wsb + 12288 * KB);    // 0.25 MB
  ushort* qrb    = (ushort*)(wsb + 12544 * KB);    // 1 MB
  ushort* krb    = (ushort*)(wsb + 13568 * KB);    // 1 MB
  ushort* svT    = (ushort*)(wsb + 14592 * KB);    // 0.25 MB
  float*  asym   = (float*)(wsb + 14848 * KB);     // 2 MB
  ushort* attb   = (ushort*)(wsb + 16896 * KB);    // 1 MB
  ushort* rel_bT = (ushort*)(wsb + 17920 * KB);    // 8 MB

  prep_kernel<<<dim3(32, 32, 7), 256, 0, stream>>>(x, symbols, wq_attn, wk_attn,
                                                   wq_rel, wk_rel, wv, wo,
                                                   xb, symb, wqT, wkT, wqrT, wkrT, wvT, woT);
  proj_mfma<<<dim3(16, 8, 5), 256, 0, stream>>>(xb, symb, wqT, wkT, wqrT, wkrT, wvT,
                                                qb, kb, qrb, krb, svT, fcos, fsin);
  relflash_kernel<<<dim3(768), 256, 0, stream>>>(qb, kb, svT, qrb, krb, attn, asym,
                                                 rel, rel_bT);
  tker_combine<<<dim3(128), 256, 0, stream>>>(attn, rel_bT, asym, wr, attb);
  out_mfma<<<dim3(32, 8), 256, 0, stream>>>(attb, woT, out);
}

// Round 7
// 152.500 us; speedup vs baseline: 1.1115x; 1.0027x over previous
//
#include <hip/hip_runtime.h>
#include <math.h>

// B=1, L=512, D=1024, NH=16, NKV=4, NR=16, HD=RD=64
#define ATTN_SCALE 0.125f
#define REL_SCALE 0.125f

using ushort = unsigned short;
using bf16x8 = __attribute__((ext_vector_type(8))) __bf16;
using floatx4 = __attribute__((ext_vector_type(4))) float;
using ushort8 = __attribute__((ext_vector_type(8))) ushort;
using ushort4v = __attribute__((ext_vector_type(4))) ushort;

__device__ __forceinline__ ushort f2bf(float x) {
  unsigned int u = __builtin_bit_cast(unsigned int, x);
  u += 0x7fffu + ((u >> 16) & 1u);  // RNE
  return (ushort)(u >> 16);
}

// ---------------------------------------------------------------------------
// prep: z=0..5 weight transpose+convert (conflict-free 32x33 LDS transpose);
//       z=6 x/symbols fp32->bf16
// ---------------------------------------------------------------------------
__global__ __launch_bounds__(256) void prep_kernel(
    const float* __restrict__ x, const float* __restrict__ sym,
    const float* __restrict__ wq, const float* __restrict__ wk,
    const float* __restrict__ wqr, const float* __restrict__ wkr,
    const float* __restrict__ wv, const float* __restrict__ wo,
    ushort* __restrict__ xb, ushort* __restrict__ symb,
    ushort* __restrict__ wqT, ushort* __restrict__ wkT, ushort* __restrict__ wqrT,
    ushort* __restrict__ wkrT, ushort* __restrict__ wvT, ushort* __restrict__ woT) {
  if (blockIdx.z == 6) {
    int b = blockIdx.y * 32 + blockIdx.x;
    if (b >= 512) return;
    int idx = b * 256 + threadIdx.x;
    int i4 = idx << 2;
    float4 v = *(const float4*)(x + i4);
    uint2 o;
    o.x = (unsigned)f2bf(v.x) | ((unsigned)f2bf(v.y) << 16);
    o.y = (unsigned)f2bf(v.z) | ((unsigned)f2bf(v.w) << 16);
    *(uint2*)(xb + i4) = o;
    float4 w = *(const float4*)(sym + i4);
    o.x = (unsigned)f2bf(w.x) | ((unsigned)f2bf(w.y) << 16);
    o.y = (unsigned)f2bf(w.z) | ((unsigned)f2bf(w.w) << 16);
    *(uint2*)(symb + i4) = o;
    return;
  }
  __shared__ ushort t[32][33];
  const float* in;
  ushort* out;
  int N;
  switch (blockIdx.z) {
    case 0: in = wq;  out = wqT;  N = 1024; break;
    case 1: in = wk;  out = wkT;  N = 256;  break;
    case 2: in = wqr; out = wqrT; N = 1024; break;
    case 3: in = wkr; out = wkrT; N = 1024; break;
    case 4: in = wv;  out = wvT;  N = 256;  break;
    default: in = wo; out = woT;  N = 1024; break;
  }
  int n0 = blockIdx.x << 5;
  if (n0 >= N) return;
  int k0 = blockIdx.y << 5;
  int tx = threadIdx.x & 31, ty = threadIdx.x >> 5;
#pragma unroll
  for (int rr = 0; rr < 32; rr += 8)
    t[ty + rr][tx] = f2bf(in[(size_t)(k0 + ty + rr) * N + n0 + tx]);
  __syncthreads();
#pragma unroll
  for (int rr = 0; rr < 32; rr += 8)
    out[(size_t)(n0 + ty + rr) * 1024 + k0 + tx] = t[tx][ty + rr];
}

// ---------------------------------------------------------------------------
// proj: 64x32 tiles (2x block count vs 64x64 -> 2x latency hiding).
// z = {q(+rope), k(+rope), qr, kr, sv(->svT)} — all-bf16 operands.
// ---------------------------------------------------------------------------
__global__ __launch_bounds__(256) void proj_mfma(
    const ushort* __restrict__ xb, const ushort* __restrict__ symb,
    const ushort* __restrict__ wqT, const ushort* __restrict__ wkT,
    const ushort* __restrict__ wqrT, const ushort* __restrict__ wkrT,
    const ushort* __restrict__ wvT,
    ushort* __restrict__ qb, ushort* __restrict__ kb, ushort* __restrict__ qrb,
    ushort* __restrict__ krb, ushort* __restrict__ svT,
    const float* __restrict__ fcos, const float* __restrict__ fsin) {
  __shared__ ushort As[64][72];
  __shared__ ushort Bs[32][72];
  const int z = blockIdx.z;
  const ushort* A = xb;
  const ushort* Bt;
  ushort* C;
  int N;
  switch (z) {
    case 0: Bt = wqT;  C = qb;  N = 1024; break;
    case 1: Bt = wkT;  C = kb;  N = 256;  break;
    case 2: Bt = wqrT; C = qrb; N = 1024; break;
    case 3: Bt = wkrT; C = krb; N = 1024; break;
    default: A = symb; Bt = wvT; C = svT; N = 256; break;
  }
  const int bn = blockIdx.x << 5;
  if (bn >= N) return;
  const int bm = blockIdx.y << 6;
  const int tid = threadIdx.x;
  const int sr = tid >> 2, sc = (tid & 3) << 4;  // A stage: 16 elems
  const int br = tid >> 3, bc = (tid & 7) << 3;  // B stage: 8 elems
  const int lane = tid & 63;
  const int wy = (tid >> 7) & 1, wx = (tid >> 6) & 1;
  const int lm = lane & 15, lq = lane >> 4;
  const ushort* a_rd = &As[32 * wy + lm][lq * 8];
  const ushort* b_rd = &Bs[16 * wx + lm][lq * 8];
  floatx4 acc[2] = {};
  for (int k0 = 0; k0 < 1024; k0 += 64) {
    const ushort* Ap = A + (size_t)(bm + sr) * 1024 + k0 + sc;
    ushort8 av0 = *(const ushort8*)Ap;
    ushort8 av1 = *(const ushort8*)(Ap + 8);
    ushort8 bv = *(const ushort8*)(Bt + (size_t)(bn + br) * 1024 + k0 + bc);
    __syncthreads();
    *(ushort8*)&As[sr][sc] = av0;
    *(ushort8*)&As[sr][sc + 8] = av1;
    *(ushort8*)&Bs[br][bc] = bv;
    __syncthreads();
#pragma unroll
    for (int kh = 0; kh < 2; ++kh) {
      bf16x8 a0 = *(const bf16x8*)(a_rd + kh * 32);
      bf16x8 a1 = *(const bf16x8*)(a_rd + 16 * 72 + kh * 32);
      bf16x8 b0 = *(const bf16x8*)(b_rd + kh * 32);
      acc[0] = __builtin_amdgcn_mfma_f32_16x16x32_bf16(a0, b0, acc[0], 0, 0, 0);
      acc[1] = __builtin_amdgcn_mfma_f32_16x16x32_bf16(a1, b0, acc[1], 0, 0, 0);
    }
  }
  if (z <= 1) {
    // fused RoPE: lanes lm, lm^1 hold the (even,odd) pair of d
#pragma unroll
    for (int sy = 0; sy < 2; ++sy)
#pragma unroll
      for (int e = 0; e < 4; ++e) {
        int row = bm + 32 * wy + 16 * sy + 4 * lq + e;
        int col = bn + 16 * wx + lm;
        float v = acc[sy][e];
        float pv = __shfl_xor(v, 1);
        int d = col & 63, p = d >> 1;
        float c = fcos[(row << 5) + p], s = fsin[(row << 5) + p];
        float o = (d & 1) ? fmaf(pv, s, v * c) : fmaf(v, c, -pv * s);
        C[(size_t)row * N + col] = f2bf(o);
      }
  } else if (z == 4) {
#pragma unroll
    for (int sy = 0; sy < 2; ++sy)
#pragma unroll
      for (int e = 0; e < 4; ++e) {
        int row = bm + 32 * wy + 16 * sy + 4 * lq + e;
        int col = bn + 16 * wx + lm;
        svT[(size_t)col * 512 + row] = f2bf(acc[sy][e]);
      }
  } else {
#pragma unroll
    for (int sy = 0; sy < 2; ++sy)
#pragma unroll
      for (int e = 0; e < 4; ++e) {
        int row = bm + 32 * wy + 16 * sy + 4 * lq + e;
        int col = bn + 16 * wx + lm;
        C[(size_t)row * N + col] = f2bf(acc[sy][e]);
      }
  }
}

// ---------------------------------------------------------------------------
// relflash: bx<512 -> flash (scores+softmax+attn fp32 + attn_b bf16 + asym);
//           bx>=512 -> relations (fp32 rel r-innermost + bf16 rel_bT[i][r][j]).
// ---------------------------------------------------------------------------
__global__ __launch_bounds__(256) void relflash_kernel(
    const ushort* __restrict__ qb, const ushort* __restrict__ kb,
    const ushort* __restrict__ svT, const ushort* __restrict__ qrb,
    const ushort* __restrict__ krb, float* __restrict__ attn,
    ushort* __restrict__ attn_b, float* __restrict__ asym,
    float* __restrict__ rel, ushort* __restrict__ rel_bT) {
  __shared__ float S[16][516];
  __shared__ ushort P[16][520];
  const int bx = blockIdx.x;
  const int tid = threadIdx.x, wave = tid >> 6, lane = tid & 63;
  const int lm = lane & 15, lq = lane >> 4;
  if (bx >= 512) {
    // ---- relations ----
    const int b = bx - 512;
    const int bi0 = (b >> 4) << 5, bj0 = (b & 15) << 5;
    const int ib = bi0 + ((wave >> 1) << 4), jb = bj0 + ((wave & 1) << 4);
    const ushort* qrow = qrb + (size_t)(ib + lm) * 1024 + lq * 8;
    const ushort* krow = krb + (size_t)(jb + lm) * 1024 + lq * 8;
#pragma unroll
    for (int rq = 0; rq < 4; ++rq) {
      floatx4 acc[4];
#pragma unroll
      for (int rr = 0; rr < 4; ++rr) {
        int roff = ((rq << 2) + rr) << 6;
        bf16x8 a0 = *(const bf16x8*)(qrow + roff);
        bf16x8 a1 = *(const bf16x8*)(qrow + roff + 32);
        bf16x8 b0 = *(const bf16x8*)(krow + roff);
        bf16x8 b1 = *(const bf16x8*)(krow + roff + 32);
        floatx4 t = {0.f, 0.f, 0.f, 0.f};
        t = __builtin_amdgcn_mfma_f32_16x16x32_bf16(a0, b0, t, 0, 0, 0);
        t = __builtin_amdgcn_mfma_f32_16x16x32_bf16(a1, b1, t, 0, 0, 0);
        acc[rr] = t;
      }
#pragma unroll
      for (int e = 0; e < 4; ++e) {
        int i = ib + 4 * lq + e, j = jb + lm;
        float4 v = make_float4(acc[0][e] * REL_SCALE, acc[1][e] * REL_SCALE,
                               acc[2][e] * REL_SCALE, acc[3][e] * REL_SCALE);
        *(float4*)(rel + ((size_t)i * 512 + j) * 16 + (rq << 2)) = v;
        size_t tb = (size_t)i * 8192 + (size_t)(rq << 2) * 512 + j;
        rel_bT[tb]        = f2bf(v.x);
        rel_bT[tb + 512]  = f2bf(v.y);
        rel_bT[tb + 1024] = f2bf(v.z);
        rel_bT[tb + 1536] = f2bf(v.w);
      }
    }
    return;
  }
  // ---- flash ----
  const int h = bx >> 5, it = 31 - (bx & 31);  // longest tiles dispatched first
  const int i0 = it << 4, kv = h >> 2;
  const int ntiles = it + 1;
  const ushort* qrow = qb + (size_t)(i0 + lm) * 1024 + (h << 6) + lq * 8;
  bf16x8 a0 = *(const bf16x8*)(qrow);
  bf16x8 a1 = *(const bf16x8*)(qrow + 32);
  for (int jt = wave; jt < ntiles; jt += 4) {
    int jb = jt << 4;
    const ushort* krow = kb + (size_t)(jb + lm) * 256 + (kv << 6) + lq * 8;
    bf16x8 b0 = *(const bf16x8*)(krow);
    bf16x8 b1 = *(const bf16x8*)(krow + 32);
    floatx4 acc = {0.f, 0.f, 0.f, 0.f};
    acc = __builtin_amdgcn_mfma_f32_16x16x32_bf16(a0, b0, acc, 0, 0, 0);
    acc = __builtin_amdgcn_mfma_f32_16x16x32_bf16(a1, b1, acc, 0, 0, 0);
#pragma unroll
    for (int e = 0; e < 4; ++e) S[4 * lq + e][jb + lm] = acc[e] * ATTN_SCALE;
  }
  __syncthreads();
  const int row = tid >> 4, t16 = tid & 15;
  const int i = i0 + row;
  const int nj = ntiles << 4;
  float m = -INFINITY;
  for (int s = 0; (s << 6) < nj; ++s) {
    int j4 = (t16 << 2) + (s << 6);
    float4 v = *(const float4*)&S[row][j4];
    if (j4 + 0 <= i) m = fmaxf(m, v.x);
    if (j4 + 1 <= i) m = fmaxf(m, v.y);
    if (j4 + 2 <= i) m = fmaxf(m, v.z);
    if (j4 + 3 <= i) m = fmaxf(m, v.w);
  }
#pragma unroll
  for (int o = 8; o; o >>= 1) m = fmaxf(m, __shfl_xor(m, o, 16));
  float sum = 0.f;
  for (int s = 0; (s << 6) < nj; ++s) {
    int j4 = (t16 << 2) + (s << 6);
    float4 v = *(const float4*)&S[row][j4];
    v.x = (j4 + 0 <= i) ? __expf(v.x - m) : 0.f;
    v.y = (j4 + 1 <= i) ? __expf(v.y - m) : 0.f;
    v.z = (j4 + 2 <= i) ? __expf(v.z - m) : 0.f;
    v.w = (j4 + 3 <= i) ? __expf(v.w - m) : 0.f;
    sum += v.x + v.y + v.z + v.w;
    *(float4*)&S[row][j4] = v;
  }
#pragma unroll
  for (int o = 8; o; o >>= 1) sum += __shfl_xor(sum, o, 16);
  const float inv = 1.f / sum;
  float* arow = attn + (size_t)h * 262144 + (size_t)i * 512;
  ushort* abrow = attn_b + (size_t)i * 8192 + (size_t)h * 512;
  for (int s = 0; s < 8; ++s) {
    int j4 = (t16 << 2) + (s << 6);
    float4 o4 = {0.f, 0.f, 0.f, 0.f};
    if (j4 < nj) {
      float4 v = *(const float4*)&S[row][j4];
      o4.x = v.x * inv;
      o4.y = v.y * inv;
      o4.z = v.z * inv;
      o4.w = v.w * inv;
    }
    *(float4*)(arow + j4) = o4;  // exact zeros above diagonal
    ushort4v p4;
    p4.x = f2bf(o4.x); p4.y = f2bf(o4.y); p4.z = f2bf(o4.z); p4.w = f2bf(o4.w);
    *(ushort4v*)&P[row][j4] = p4;
    *(ushort4v*)(abrow + j4) = p4;  // bf16 attn copy for tker
  }
  __syncthreads();
  // attended_symbols: wave w owns d-range w*16
  const int dbase = wave << 4;
  floatx4 acc2 = {0.f, 0.f, 0.f, 0.f};
  const ushort* svrow = svT + (size_t)((kv << 6) + dbase + lm) * 512;
  const int kmax = (nj + 31) & ~31;  // P zero-filled to 512
  for (int kt = 0; kt < kmax; kt += 32) {
    bf16x8 pa = *(const bf16x8*)&P[lm][kt + lq * 8];
    bf16x8 pb = *(const bf16x8*)(svrow + kt + lq * 8);
    acc2 = __builtin_amdgcn_mfma_f32_16x16x32_bf16(pa, pb, acc2, 0, 0, 0);
  }
#pragma unroll
  for (int e = 0; e < 4; ++e)
    asym[(size_t)(i0 + 4 * lq + e) * 1024 + (h << 6) + dbase + lm] = acc2[e];
}

// ---------------------------------------------------------------------------
// tker+combine via MFMA: per i (wave w -> i = 4*bx + w),
// T[16h x 16r] = attn_b[i] (16x512 bf16) * rel_bT[i]^T (16x512 bf16).
// Then att[i,h,d] = asym + sum_r T[h][r]*wr[r][h*64+d] via LDS Ts.
// ---------------------------------------------------------------------------
__global__ __launch_bounds__(256) void tker_combine(const ushort* __restrict__ attn_b,
                                                    const ushort* __restrict__ rel_bT,
                                                    const float* __restrict__ asym,
                                                    const float* __restrict__ wr,
                                                    ushort* __restrict__ attb) {
  const int i0 = blockIdx.x << 2;
  const int tid = threadIdx.x, wave = tid >> 6, lane = tid & 63;
  const int lm = lane & 15, lq = lane >> 4;
  const int i = i0 + wave;
  __shared__ float Ts[4][16][17];
  floatx4 acc = {0.f, 0.f, 0.f, 0.f};
  const ushort* arow = attn_b + (size_t)i * 8192 + (size_t)lm * 512;  // h = lm
  const ushort* brow = rel_bT + (size_t)i * 8192 + (size_t)lm * 512;  // r = lm
  const int ktiles = (i >> 5) + 1;  // attn_b is exactly 0 for j > i
  for (int kt = 0; kt < ktiles; ++kt) {
    int k = (kt << 5) + lq * 8;
    bf16x8 a = *(const bf16x8*)(arow + k);
    bf16x8 b = *(const bf16x8*)(brow + k);
    acc = __builtin_amdgcn_mfma_f32_16x16x32_bf16(a, b, acc, 0, 0, 0);
  }
  // C layout: col(lm)=r, row(4*lq+e)=h
#pragma unroll
  for (int e = 0; e < 4; ++e) Ts[wave][4 * lq + e][lm] = acc[e];
  __syncthreads();
  const int hc = tid >> 4, d4 = (tid & 15) << 2;
  float4 o[4];
#pragma unroll
  for (int iw = 0; iw < 4; ++iw)
    o[iw] = *(const float4*)(asym + (size_t)(i0 + iw) * 1024 + (hc << 6) + d4);
#pragma unroll
  for (int rr = 0; rr < 16; ++rr) {
    float4 w4 = *(const float4*)(wr + (size_t)rr * 1024 + (hc << 6) + d4);
#pragma unroll
    for (int iw = 0; iw < 4; ++iw) {
      float tv = Ts[iw][hc][rr];
      o[iw].x = fmaf(tv, w4.x, o[iw].x);
      o[iw].y = fmaf(tv, w4.y, o[iw].y);
      o[iw].z = fmaf(tv, w4.z, o[iw].z);
      o[iw].w = fmaf(tv, w4.w, o[iw].w);
    }
  }
#pragma unroll
  for (int iw = 0; iw < 4; ++iw) {
    ushort4v ob;
    ob.x = f2bf(o[iw].x); ob.y = f2bf(o[iw].y);
    ob.z = f2bf(o[iw].z); ob.w = f2bf(o[iw].w);
    *(ushort4v*)(attb + (size_t)(i0 + iw) * 1024 + (hc << 6) + d4) = ob;
  }
}

// ---------------------------------------------------------------------------
// out = attb @ wo: 64x32 tiles (256 blocks), bf16 operands (woT from prep).
// ---------------------------------------------------------------------------
__global__ __launch_bounds__(256) void out_mfma(const ushort* __restrict__ attb,
                                                const ushort* __restrict__ woT,
                                                float* __restrict__ out) {
  __shared__ ushort As[64][72];
  __shared__ ushort Bs[32][72];
  const int bn = blockIdx.x << 5, bm = blockIdx.y << 6;
  const int tid = threadIdx.x;
  const int sr = tid >> 2, sc = (tid & 3) << 4;
  const int br = tid >> 3, bc = (tid & 7) << 3;
  const int lane = tid & 63;
  const int wy = (tid >> 7) & 1, wx = (tid >> 6) & 1;
  const int lm = lane & 15, lq = lane >> 4;
  const ushort* a_rd = &As[32 * wy + lm][lq * 8];
  const ushort* b_rd = &Bs[16 * wx + lm][lq * 8];
  floatx4 acc[2] = {};
  for (int k0 = 0; k0 < 1024; k0 += 64) {
    const ushort* Ap = attb + (size_t)(bm + sr) * 1024 + k0 + sc;
    ushort8 av0 = *(const ushort8*)Ap;
    ushort8 av1 = *(const ushort8*)(Ap + 8);
    ushort8 bv = *(const ushort8*)(woT + (size_t)(bn + br) * 1024 + k0 + bc);
    __syncthreads();
    *(ushort8*)&As[sr][sc] = av0;
    *(ushort8*)&As[sr][sc + 8] = av1;
    *(ushort8*)&Bs[br][bc] = bv;
    __syncthreads();
#pragma unroll
    for (int kh = 0; kh < 2; ++kh) {
      bf16x8 a0 = *(const bf16x8*)(a_rd + kh * 32);
      bf16x8 a1 = *(const bf16x8*)(a_rd + 16 * 72 + kh * 32);
      bf16x8 b0 = *(const bf16x8*)(b_rd + kh * 32);
      acc[0] = __builtin_amdgcn_mfma_f32_16x16x32_bf16(a0, b0, acc[0], 0, 0, 0);
      acc[1] = __builtin_amdgcn_mfma_f32_16x16x32_bf16(a1, b0, acc[1], 0, 0, 0);
    }
  }
#pragma unroll
  for (int sy = 0; sy < 2; ++sy)
#pragma unroll
    for (int e = 0; e < 4; ++e) {
      int row = bm + 32 * wy + 16 * sy + 4 * lq + e;
      int col = bn + 16 * wx + lm;
      out[(size_t)row * 1024 + col] = acc[sy][e];
    }
}

extern "C" void kernel_launch(void* const* d_in, const int* in_sizes, int n_in,
                              void* d_out, int out_size, void* d_ws, size_t ws_size,
                              hipStream_t stream) {
  const float* x       = (const float*)d_in[0];
  const float* symbols = (const float*)d_in[1];
  const float* fcos    = (const float*)d_in[2];
  const float* fsin    = (const float*)d_in[3];
  const float* wq_attn = (const float*)d_in[4];
  const float* wk_attn = (const float*)d_in[5];
  const float* wq_rel  = (const float*)d_in[6];
  const float* wk_rel  = (const float*)d_in[7];
  const float* wr      = (const float*)d_in[8];
  const float* wv      = (const float*)d_in[9];
  const float* wo      = (const float*)d_in[10];

  float* out  = (float*)d_out;   // 512*1024
  float* attn = out + 524288;    // 16*512*512
  float* rel  = attn + 4194304;  // 512*512*16

  char* wsb = (char*)d_ws;
  const size_t KB = 1024;
  ushort* xb     = (ushort*)(wsb);                 // 1 MB
  ushort* symb   = (ushort*)(wsb + 1024 * KB);     // 1 MB
  ushort* wqT    = (ushort*)(wsb + 2048 * KB);     // 2 MB
  ushort* wkT    = (ushort*)(wsb + 4096 * KB);     // 0.5 MB
  ushort* wqrT   = (ushort*)(wsb + 4608 * KB);     // 2 MB
  ushort* wkrT   = (ushort*)(wsb + 6656 * KB);     // 2 MB
  ushort* wvT    = (ushort*)(wsb + 8704 * KB);     // 0.5 MB
  ushort* woT    = (ushort*)(wsb + 9216 * KB);     // 2 MB
  ushort* qb     = (ushort*)(wsb + 11264 * KB);    // 1 MB
  ushort* kb     = (ushort*)(wsb + 12288 * KB);    // 0.25 MB
  ushort* qrb    = (ushort*)(wsb + 12544 * KB);    // 1 MB
  ushort* krb    = (ushort*)(wsb + 13568 * KB);    // 1 MB
  ushort* svT    = (ushort*)(wsb + 14592 * KB);    // 0.25 MB
  float*  asym   = (float*)(wsb + 14848 * KB);     // 2 MB
  ushort* attb   = (ushort*)(wsb + 16896 * KB);    // 1 MB
  ushort* rel_bT = (ushort*)(wsb + 17920 * KB);    // 8 MB
  ushort* attn_b = (ushort*)(wsb + 26112 * KB);    // 8 MB

  prep_kernel<<<dim3(32, 32, 7), 256, 0, stream>>>(x, symbols, wq_attn, wk_attn,
                                                   wq_rel, wk_rel, wv, wo,
                                                   xb, symb, wqT, wkT, wqrT, wkrT, wvT, woT);
  proj_mfma<<<dim3(32, 8, 5), 256, 0, stream>>>(xb, symb, wqT, wkT, wqrT, wkrT, wvT,
                                                qb, kb, qrb, krb, svT, fcos, fsin);
  relflash_kernel<<<dim3(768), 256, 0, stream>>>(qb, kb, svT, qrb, krb, attn, attn_b,
                                                 asym, rel, rel_bT);
  tker_combine<<<dim3(128), 256, 0, stream>>>(attn_b, rel_bT, asym, wr, attb);
  out_mfma<<<dim3(32, 8), 256, 0, stream>>>(attb, woT, out);
}